// Round 4
// baseline (257.061 us; speedup 1.0000x reference)
//
#include <hip/hip_runtime.h>

#define N_ANCHORS 5000
#define N_CLASSES 80
#define OUT_COLS  84
#define MAX_BOXES 300
#define SCORE_THR 0.05f

#define SORT_PAD  5056
#define NB        4096
#define BLOCK     1024
#define SLOTS     8
#define DONEP     0x40000000
#define NIW       6            // intra workers: wv 1..6
#define NSW       9            // sweeps: wv 7..15

typedef unsigned long long u64;
typedef unsigned int u32;

#define WG __HIP_MEMORY_SCOPE_WORKGROUP

__device__ __forceinline__ float readlane_f(float v, int l) {
    return __int_as_float(__builtin_amdgcn_readlane(__float_as_int(v), l));
}
__device__ __forceinline__ u32 aload(u32* p) {
    return __hip_atomic_load(p, __ATOMIC_ACQUIRE, WG);
}
// monotone score->bucket map; mirrored so chunk 0 = HIGHEST scores
__device__ __forceinline__ int bucket_of(float s) {
    float u = sqrtf(s);
    int b = (int)((u - 0.2236f) * 5275.0f);
    return (NB - 1) - min(max(b, 0), NB - 1);
}
// IoU(a,q) > 0.5  <=>  3*inter > aa+aq.  Single clamp: all real areas >= 1
// so aa+aq > 0; if ih < 0 then iw_cl*ih <= 0 < aa+aq -> false, matching the
// fully-clamped form bit-for-bit.  Sentinel q (1e9^4, aq=1e18) -> false.
__device__ __forceinline__ bool iou3(float4 a, float aa, float4 q, float aq) {
    float iw = fmaxf(fminf(a.z, q.z) - fmaxf(a.x, q.x), 0.0f);
    float ih = fminf(a.w, q.w) - fmaxf(a.y, q.y);
    return 3.0f * (iw * ih) > aa + aq;
}

// LDS: lk[5056]u64 @0 | hist[4096]u32 @40448 (post-sort aliased:
//   Iring 8*64 u64 @40448 | Bring 8*64 f4 @44544 | kout 304 u64 @52736)
// | kbox 304 f4 @56832 | karea 304 f32 @61696 | KS @62912 | wtot @62976
// | KBa @63040 | flagI @63072 | flagK @63104 | prog @63136 | kcnt @63140
__global__ __launch_bounds__(BLOCK, 1) void nms(const float* __restrict__ cls,
                                                const float4* __restrict__ boxes4,
                                                float* __restrict__ out) {
    __shared__ __align__(16) char SMEM[63168];
    u64*    lk    = (u64*)SMEM;
    u32*    hist  = (u32*)(SMEM + 40448);
    u64*    Iring = (u64*)(SMEM + 40448);
    float4* Bring = (float4*)(SMEM + 44544);
    u64*    kout  = (u64*)(SMEM + 52736);
    float4* kbox  = (float4*)(SMEM + 56832);   // 304 slots, sentinel-padded
    float*  karea = (float*)(SMEM + 61696);    // kept areas, sentinel 1e18
    u64*    KS    = (u64*)(SMEM + 62912);
    u32*    wtot  = (u32*)(SMEM + 62976);
    u32*    KBa   = (u32*)(SMEM + 63040);
    u32*    flagI = (u32*)(SMEM + 63072);
    u32*    flagK = (u32*)(SMEM + 63104);
    u32*    prog  = (u32*)(SMEM + 63136);
    u32*    kcnt  = (u32*)(SMEM + 63140);

    const int c = blockIdx.x;
    const int t = threadIdx.x;
    const int lane = t & 63;
    const int wv = t >> 6;
    const float* boxesf = (const float*)boxes4;

    // ---------- fused prep ----------
    u32 sb[5];
    #pragma unroll
    for (int m = 0; m < 5; ++m) {
        int j = m * BLOCK + t;
        float v = (j < N_ANCHORS) ? cls[(size_t)j * N_CLASSES + c] : 0.0f;
        sb[m] = (v > SCORE_THR) ? __float_as_uint(v) : 0u;
    }
    for (int i = t; i < N_ANCHORS; i += BLOCK)
        out[(size_t)i * OUT_COLS + 4 + c] = 0.0f;
    if (c < 4)
        for (int i = t; i < N_ANCHORS; i += BLOCK)
            out[(size_t)i * OUT_COLS + c] = boxesf[(size_t)i * 4 + c];

    // ---------- sort phase (all 16 waves) ----------
    for (int b = t; b < NB; b += BLOCK) hist[b] = 0u;
    if (t < 304) { kbox[t] = make_float4(1e9f, 1e9f, 1e9f, 1e9f); karea[t] = 1e18f; }
    if (t < SLOTS) { flagI[t] = 0u; flagK[t] = 0u; }
    if (t == 0) { *prog = 0u; *kcnt = 0u; }
    __syncthreads();
    #pragma unroll
    for (int m = 0; m < 5; ++m)
        if (sb[m]) atomicAdd(&hist[bucket_of(__uint_as_float(sb[m]))], 1u);
    __syncthreads();

    const int hbase = t * 4;
    u32 vals[4]; u32 run = 0;
    #pragma unroll
    for (int k = 0; k < 4; ++k) { run += hist[hbase + k]; vals[k] = run; }
    u32 x = run;
    #pragma unroll
    for (int off = 1; off < 64; off <<= 1) { u32 y = __shfl_up(x, off); if (lane >= off) x += y; }
    if (lane == 63) wtot[wv] = x;
    __syncthreads();
    u32 woff = 0;
    for (int w = 0; w < wv; ++w) woff += wtot[w];
    const u32 exb = woff + x - run;
    #pragma unroll
    for (int k = 0; k < 4; ++k) hist[hbase + k] = exb + (k ? vals[k - 1] : 0u);
    __syncthreads();
    #pragma unroll
    for (int m = 0; m < 5; ++m) {
        if (sb[m]) {
            int j = m * BLOCK + t;
            u32 pos = atomicAdd(&hist[bucket_of(__uint_as_float(sb[m]))], 1u);
            lk[pos] = ((u64)sb[m] << 32) | (u32)(~(u32)j);
        }
    }
    __syncthreads();
    const int total = (int)hist[NB - 1];
    for (int v = total + t; v < SORT_PAD; v += BLOCK) lk[v] = 0ull;
    for (int b = hbase; b < hbase + 4; ++b) {
        int s0 = b ? (int)hist[b - 1] : 0;
        int e  = (int)hist[b];
        for (int i = s0 + 1; i < e; ++i) {
            u64 key = lk[i]; int q = i - 1;
            while (q >= s0 && lk[q] < key) { lk[q + 1] = lk[q]; --q; }
            lk[q + 1] = key;
        }
    }
    __syncthreads();                    // LAST barrier; roles diverge
    const int nch = (total + 63) >> 6;

    if (wv >= 1 && wv <= NIW) {
        // ======= intra workers: full 64x64 IoU matrix (independent) =======
        for (int j = wv - 1; j < nch; j += NIW) {
            const int slot = j & (SLOTS - 1);
            u64 e = lk[j * 64 + lane];
            u32 jj = e ? ~(u32)e : 0u;
            float4 bx = boxes4[jj];                      // issued before gate
            float ar = (bx.z - bx.x) * (bx.w - bx.y);
            u32 p;
            for (;;) {
                p = aload(prog);
                if ((int)p >= j - (SLOTS - 1)) break;
                __builtin_amdgcn_s_sleep(2);
            }
            if (p >= DONEP) return;
            u64 word = 0ull;
            #pragma unroll 16
            for (int q = 0; q < 64; ++q) {
                float4 o;
                o.x = readlane_f(bx.x, q); o.y = readlane_f(bx.y, q);
                o.z = readlane_f(bx.z, q); o.w = readlane_f(bx.w, q);
                float aq = readlane_f(ar, q);
                float iw = fmaxf(fminf(bx.z, o.z) - fmaxf(bx.x, o.x), 0.0f);
                float ih = fminf(bx.w, o.w) - fmaxf(bx.y, o.y);
                if (3.0f * (iw * ih) > ar + aq) word |= (1ull << q);
            }
            Iring[slot * 64 + lane] = word;
            if (lane == 0)
                __hip_atomic_store(&flagI[slot], (u32)(j + 1), __ATOMIC_RELEASE, WG);
        }
        return;
    }
    if (wv > NIW) {
        // ======= sweeps: kept-broadcast, lane-parallel-candidate =======
        for (int j = wv - (NIW + 1); j < nch; j += NSW) {
            const int slot = j & (SLOTS - 1);
            u64 e = lk[j * 64 + lane];
            bool validL = (e != 0ull);
            u32 jj = validL ? ~(u32)e : 0u;
            float4 bx = boxes4[jj];                      // issued before gate
            float ar = (bx.z - bx.x) * (bx.w - bx.y);
            u32 p;
            for (;;) {                                   // slot-free gate
                p = aload(prog);
                if ((int)p >= j - (SLOTS - 1)) break;
                __builtin_amdgcn_s_sleep(2);
            }
            if (p >= DONEP) return;
            Bring[slot * 64 + lane] = bx;
            bool sup = !validL;                          // invalid = suppressed
            u32 ka = aload(kcnt);
            // stage A: own candidate vs kept[0..ka) via uniform LDS broadcast
            #pragma unroll 2
            for (u32 r = 0; r < ka; r += 4) {
                float4 q0 = kbox[r], q1 = kbox[r + 1], q2 = kbox[r + 2], q3 = kbox[r + 3];
                float4 a4 = *(const float4*)(karea + r);
                sup = sup | iou3(bx, ar, q0, a4.x) | iou3(bx, ar, q1, a4.y)
                          | iou3(bx, ar, q2, a4.z) | iou3(bx, ar, q3, a4.w);
                if ((r & 28u) == 28u && !__ballot(!sup)) break;   // all done
            }
            for (;;) {                                   // stage-B gate
                p = aload(prog);
                if ((int)p >= j - 2) break;
                __builtin_amdgcn_s_sleep(1);
            }
            u32 kb2 = (p >= DONEP) ? ka : aload(kcnt);
            if (kb2 < ka) kb2 = ka;
            u32 r1 = (kb2 + 3) & ~3u;                    // top-up: recent keeps (few)
            for (u32 r = ka & ~3u; r < r1; r += 4) {
                float4 q0 = kbox[r], q1 = kbox[r + 1], q2 = kbox[r + 2], q3 = kbox[r + 3];
                float4 a4 = *(const float4*)(karea + r);
                sup = sup | iou3(bx, ar, q0, a4.x) | iou3(bx, ar, q1, a4.y)
                          | iou3(bx, ar, q2, a4.z) | iou3(bx, ar, q3, a4.w);
            }
            u64 ksf = __ballot(sup);
            if (lane == 0) {
                KS[slot] = ksf; KBa[slot] = kb2;
                __hip_atomic_store(&flagK[slot], (u32)(j + 1), __ATOMIC_RELEASE, WG);
            }
            if (p >= DONEP) return;
        }
        return;
    }

    // ======= wave 0: serial scan (all-LDS steady state) =======
    int kept = 0; u32 kcur = 0; bool capped = false;
    u64 key = lk[lane];                                  // chunk-0 prefetch
    for (int k = 0; k < nch; ++k) {
        const int slot = k & (SLOTS - 1);
        bool valid = (key != 0ull);
        u32 j = valid ? ~(u32)key : 0u;
        float sc = __uint_as_float((u32)(key >> 32));

        while (aload(&flagK[slot]) != (u32)(k + 1)) { }   // normally immediate
        while (aload(&flagI[slot]) != (u32)(k + 1)) { }
        u64 ks = KS[slot];
        if (ks != ~0ull) {
            u32 kb = KBa[slot];
            float4 bx = Bring[slot * 64 + lane];
            u64 I = Iring[slot * 64 + lane];              // load overlaps top-up
            float ar = (bx.z - bx.x) * (bx.w - bx.y);
            bool alive = valid && !((ks >> lane) & 1ull);
            u32 r1 = (kcur + 3) & ~3u;                    // top-up recent keeps
            for (u32 r = kb & ~3u; r < r1; r += 4) {
                float4 q0 = kbox[r], q1 = kbox[r + 1], q2 = kbox[r + 2], q3 = kbox[r + 3];
                float4 a4 = *(const float4*)(karea + r);
                bool s = iou3(bx, ar, q0, a4.x) | iou3(bx, ar, q1, a4.y)
                       | iou3(bx, ar, q2, a4.z) | iou3(bx, ar, q3, a4.w);
                alive = alive && !s;
            }
            u64 rem = __ballot(alive);
            if (rem) {
                u64 km = 0ull;
                while (rem) {                             // SALU keep chain
                    int pos = __ffsll((long long)rem) - 1;
                    km |= 1ull << pos;
                    if (++kept == MAX_BOXES) { capped = true; break; }
                    u32 lo = (u32)__builtin_amdgcn_readlane((int)(u32)I, pos);
                    u32 hi = (u32)__builtin_amdgcn_readlane((int)(u32)(I >> 32), pos);
                    rem &= ~(((u64)hi << 32) | (u64)lo);  // diag bit kills pos
                }
                if ((km >> lane) & 1ull) {
                    int rank = (int)__popcll(km & ((1ull << lane) - 1ull));
                    kbox[kcur + rank] = bx;
                    karea[kcur + rank] = ar;
                    kout[kcur + rank] = ((u64)__float_as_uint(sc) << 32) | j;
                }
                kcur += (u32)__popcll(km);
            }
        }
        if (capped) break;
        if (lane == 0) {
            __hip_atomic_store(kcnt, kcur, __ATOMIC_RELEASE, WG);
            __hip_atomic_store(prog, (u32)(k + 1), __ATOMIC_RELEASE, WG);
        }
        if (k + 1 < nch) key = lk[(k + 1) * 64 + lane];   // prefetch next chunk
    }
    if (lane == 0) __hip_atomic_store(prog, (u32)DONEP, __ATOMIC_RELEASE, WG);

    // flush buffered keeps to global (off the serial chain)
    for (u32 i = (u32)lane; i < kcur; i += 64) {
        u64 e = kout[i];
        out[(size_t)((u32)e) * OUT_COLS + 4 + c] = __uint_as_float((u32)(e >> 32));
    }
}

// ---- clock probe: 60000 dependent FMAs ~= 240k cycles.  dur_us reads out the
// effective shader clock: ~100us -> 2.4GHz, ~240us -> 1GHz, ~343us -> 0.7GHz.
__global__ void clkprobe() {
    float x = 1.0f;
    const float a = 1.0000001f, b = 1e-7f;
    for (int i = 0; i < 7500; ++i) {
        x = fmaf(x, a, b); x = fmaf(x, a, b); x = fmaf(x, a, b); x = fmaf(x, a, b);
        x = fmaf(x, a, b); x = fmaf(x, a, b); x = fmaf(x, a, b); x = fmaf(x, a, b);
    }
    asm volatile("" :: "v"(x));
}

extern "C" void kernel_launch(void* const* d_in, const int* in_sizes, int n_in,
                              void* d_out, int out_size, void* d_ws, size_t ws_size,
                              hipStream_t stream) {
    const float* cls = (const float*)d_in[1];
    float* out = (float*)d_out;
    nms<<<N_CLASSES, BLOCK, 0, stream>>>(cls, (const float4*)d_in[0], out);
    clkprobe<<<1, 64, 0, stream>>>();
}

// Round 5
// 145.200 us; speedup vs baseline: 1.7704x; 1.7704x over previous
//
#include <hip/hip_runtime.h>

#define N_ANCHORS 5000
#define N_CLASSES 80
#define OUT_COLS  84
#define MAX_BOXES 300
#define SCORE_THR 0.05f

#define SORT_PAD  5056
#define NB        4096
#define BLOCK     1024
#define SLOTS     8
#define DONEP     0x40000000
#define NIW       6            // intra workers: wv 1..6
#define NSW       9            // sweeps: wv 7..15

typedef unsigned long long u64;
typedef unsigned int u32;

#define WG __HIP_MEMORY_SCOPE_WORKGROUP

__device__ __forceinline__ float readlane_f(float v, int l) {
    return __int_as_float(__builtin_amdgcn_readlane(__float_as_int(v), l));
}
__device__ __forceinline__ u32 aload(u32* p) {
    return __hip_atomic_load(p, __ATOMIC_ACQUIRE, WG);
}
__device__ __forceinline__ u64 aload64(u64* p) {
    return __hip_atomic_load(p, __ATOMIC_ACQUIRE, WG);
}
// monotone score->bucket map; mirrored so chunk 0 = HIGHEST scores
__device__ __forceinline__ int bucket_of(float s) {
    float u = sqrtf(s);
    int b = (int)((u - 0.2236f) * 5275.0f);
    return (NB - 1) - min(max(b, 0), NB - 1);
}
// IoU(a,q) > 0.5  <=>  3*inter > aa+aq.  Single clamp: all real areas >= 1
// so aa+aq > 0; if ih < 0 then iw_cl*ih <= 0 < aa+aq -> false, matching the
// fully-clamped form bit-for-bit.  Sentinel q (1e9^4, aq=1e18) -> false.
__device__ __forceinline__ bool iou3(float4 a, float aa, float4 q, float aq) {
    float iw = fmaxf(fminf(a.z, q.z) - fmaxf(a.x, q.x), 0.0f);
    float ih = fminf(a.w, q.w) - fmaxf(a.y, q.y);
    return 3.0f * (iw * ih) > aa + aq;
}

// LDS: lk[5056]u64 @0 | hist[4096]u32 @40448 (post-sort aliased:
//   Iring 8*64 u64 @40448 | Bring 8*64 f4 @44544 | kout 304 u64 @52736)
// | kbox 304 f4 @56832 | karea 304 f32 @61696 | KS @62912 | wtot @62976
// | KBa @63040 | flagIK 8 u64 @63072 {lo=flagK, hi=flagI} | prog @63136 | kcnt @63140
__global__ __launch_bounds__(BLOCK, 1) void nms(const float* __restrict__ cls,
                                                const float4* __restrict__ boxes4,
                                                float* __restrict__ out) {
    __shared__ __align__(16) char SMEM[63168];
    u64*    lk      = (u64*)SMEM;
    u32*    hist    = (u32*)(SMEM + 40448);
    u64*    Iring   = (u64*)(SMEM + 40448);
    float4* Bring   = (float4*)(SMEM + 44544);
    u64*    kout    = (u64*)(SMEM + 52736);
    float4* kbox    = (float4*)(SMEM + 56832);   // 304 slots, sentinel-padded
    float*  karea   = (float*)(SMEM + 61696);    // kept areas, sentinel 1e18
    u64*    KS      = (u64*)(SMEM + 62912);
    u32*    wtot    = (u32*)(SMEM + 62976);
    u32*    KBa     = (u32*)(SMEM + 63040);
    u64*    flagIK  = (u64*)(SMEM + 63072);
    u32*    flagIK32= (u32*)(SMEM + 63072);
    u32*    prog    = (u32*)(SMEM + 63136);
    u32*    kcnt    = (u32*)(SMEM + 63140);

    const int c = blockIdx.x;
    const int t = threadIdx.x;
    const int lane = t & 63;
    const int wv = t >> 6;
    const float* boxesf = (const float*)boxes4;

    // ---------- fused prep ----------
    u32 sb[5];
    #pragma unroll
    for (int m = 0; m < 5; ++m) {
        int j = m * BLOCK + t;
        float v = (j < N_ANCHORS) ? cls[(size_t)j * N_CLASSES + c] : 0.0f;
        sb[m] = (v > SCORE_THR) ? __float_as_uint(v) : 0u;
    }
    for (int i = t; i < N_ANCHORS; i += BLOCK)
        out[(size_t)i * OUT_COLS + 4 + c] = 0.0f;
    if (c < 4)
        for (int i = t; i < N_ANCHORS; i += BLOCK)
            out[(size_t)i * OUT_COLS + c] = boxesf[(size_t)i * 4 + c];

    // ---------- sort phase (all 16 waves) ----------
    for (int b = t; b < NB; b += BLOCK) hist[b] = 0u;
    if (t < 304) { kbox[t] = make_float4(1e9f, 1e9f, 1e9f, 1e9f); karea[t] = 1e18f; }
    if (t < SLOTS) flagIK[t] = 0ull;
    if (t == 0) { *prog = 0u; *kcnt = 0u; }
    __syncthreads();
    #pragma unroll
    for (int m = 0; m < 5; ++m)
        if (sb[m]) atomicAdd(&hist[bucket_of(__uint_as_float(sb[m]))], 1u);
    __syncthreads();

    const int hbase = t * 4;
    u32 vals[4]; u32 run = 0;
    #pragma unroll
    for (int k = 0; k < 4; ++k) { run += hist[hbase + k]; vals[k] = run; }
    u32 x = run;
    #pragma unroll
    for (int off = 1; off < 64; off <<= 1) { u32 y = __shfl_up(x, off); if (lane >= off) x += y; }
    if (lane == 63) wtot[wv] = x;
    __syncthreads();
    u32 woff = 0;
    for (int w = 0; w < wv; ++w) woff += wtot[w];
    const u32 exb = woff + x - run;
    #pragma unroll
    for (int k = 0; k < 4; ++k) hist[hbase + k] = exb + (k ? vals[k - 1] : 0u);
    __syncthreads();
    #pragma unroll
    for (int m = 0; m < 5; ++m) {
        if (sb[m]) {
            int j = m * BLOCK + t;
            u32 pos = atomicAdd(&hist[bucket_of(__uint_as_float(sb[m]))], 1u);
            lk[pos] = ((u64)sb[m] << 32) | (u32)(~(u32)j);
        }
    }
    __syncthreads();
    const int total = (int)hist[NB - 1];
    for (int v = total + t; v < SORT_PAD; v += BLOCK) lk[v] = 0ull;
    for (int b = hbase; b < hbase + 4; ++b) {
        int s0 = b ? (int)hist[b - 1] : 0;
        int e  = (int)hist[b];
        for (int i = s0 + 1; i < e; ++i) {
            u64 key = lk[i]; int q = i - 1;
            while (q >= s0 && lk[q] < key) { lk[q + 1] = lk[q]; --q; }
            lk[q + 1] = key;
        }
    }
    __syncthreads();                    // LAST barrier; roles diverge
    const int nch = (total + 63) >> 6;

    if (wv >= 1 && wv <= NIW) {
        // ======= intra workers: full 64x64 IoU matrix (independent) =======
        for (int j = wv - 1; j < nch; j += NIW) {
            const int slot = j & (SLOTS - 1);
            u64 e = lk[j * 64 + lane];
            u32 jj = e ? ~(u32)e : 0u;
            float4 bx = boxes4[jj];                      // issued before gate
            float ar = (bx.z - bx.x) * (bx.w - bx.y);
            u32 p;
            for (;;) {
                p = aload(prog);
                if ((int)p >= j - (SLOTS - 1)) break;
                __builtin_amdgcn_s_sleep(2);
            }
            if (p >= DONEP) return;
            u64 word = 0ull;
            #pragma unroll 16
            for (int q = 0; q < 64; ++q) {
                float4 o;
                o.x = readlane_f(bx.x, q); o.y = readlane_f(bx.y, q);
                o.z = readlane_f(bx.z, q); o.w = readlane_f(bx.w, q);
                float aq = readlane_f(ar, q);
                float iw = fmaxf(fminf(bx.z, o.z) - fmaxf(bx.x, o.x), 0.0f);
                float ih = fminf(bx.w, o.w) - fmaxf(bx.y, o.y);
                if (3.0f * (iw * ih) > ar + aq) word |= (1ull << q);
            }
            Iring[slot * 64 + lane] = word;
            if (lane == 0)
                __hip_atomic_store(&flagIK32[slot * 2 + 1], (u32)(j + 1), __ATOMIC_RELEASE, WG);
        }
        return;
    }
    if (wv > NIW) {
        // ======= sweeps: kept-broadcast, lane-parallel-candidate =======
        for (int j = wv - (NIW + 1); j < nch; j += NSW) {
            const int slot = j & (SLOTS - 1);
            u64 e = lk[j * 64 + lane];
            bool validL = (e != 0ull);
            u32 jj = validL ? ~(u32)e : 0u;
            float4 bx = boxes4[jj];                      // issued before gate
            float ar = (bx.z - bx.x) * (bx.w - bx.y);
            u32 p;
            for (;;) {                                   // slot-free gate
                p = aload(prog);
                if ((int)p >= j - (SLOTS - 1)) break;
                __builtin_amdgcn_s_sleep(2);
            }
            if (p >= DONEP) return;
            Bring[slot * 64 + lane] = bx;
            bool sup = !validL;                          // invalid = suppressed
            u32 ka = aload(kcnt);
            // stage A: own candidate vs kept[0..ka) via uniform LDS broadcast
            #pragma unroll 2
            for (u32 r = 0; r < ka; r += 4) {
                float4 q0 = kbox[r], q1 = kbox[r + 1], q2 = kbox[r + 2], q3 = kbox[r + 3];
                float4 a4 = *(const float4*)(karea + r);
                sup = sup | iou3(bx, ar, q0, a4.x) | iou3(bx, ar, q1, a4.y)
                          | iou3(bx, ar, q2, a4.z) | iou3(bx, ar, q3, a4.w);
                if ((r & 28u) == 28u && !__ballot(!sup)) break;   // all done
            }
            for (;;) {                                   // stage-B gate (2-period slack)
                p = aload(prog);
                if ((int)p >= j - 2) break;
                __builtin_amdgcn_s_sleep(1);
            }
            __builtin_amdgcn_s_setprio(1);               // tail leg: mildly favored
            u32 kb2 = (p >= DONEP) ? ka : aload(kcnt);
            if (kb2 < ka) kb2 = ka;
            u32 r1 = (kb2 + 3) & ~3u;                    // top-up: recent keeps (few)
            for (u32 r = ka & ~3u; r < r1; r += 4) {
                float4 q0 = kbox[r], q1 = kbox[r + 1], q2 = kbox[r + 2], q3 = kbox[r + 3];
                float4 a4 = *(const float4*)(karea + r);
                sup = sup | iou3(bx, ar, q0, a4.x) | iou3(bx, ar, q1, a4.y)
                          | iou3(bx, ar, q2, a4.z) | iou3(bx, ar, q3, a4.w);
            }
            u64 ksf = __ballot(sup);
            if (lane == 0) {
                KS[slot] = ksf; KBa[slot] = kb2;
                __hip_atomic_store(&flagIK32[slot * 2], (u32)(j + 1), __ATOMIC_RELEASE, WG);
            }
            __builtin_amdgcn_s_setprio(0);
            if (p >= DONEP) return;
        }
        return;
    }

    // ======= wave 0: serial scan — HIGH PRIORITY (wins SIMD arbitration
    // against the 3 always-ready worker waves sharing its SIMD; during its
    // LDS-latency stalls it is not ready, so workers still progress) =======
    __builtin_amdgcn_s_setprio(3);
    int kept = 0; u32 kcur = 0; bool capped = false;
    u64 key = lk[lane];                                  // chunk-0 prefetch
    for (int k = 0; k < nch; ++k) {
        const int slot = k & (SLOTS - 1);
        bool valid = (key != 0ull);
        u32 j = valid ? ~(u32)key : 0u;
        float sc = __uint_as_float((u32)(key >> 32));

        const u64 want = ((u64)(u32)(k + 1) << 32) | (u32)(k + 1);
        while (aload64(&flagIK[slot]) != want) { }        // both flags, ONE poll
        // hoisted batch: all four ring reads issue back-to-back (one LDS wait)
        u64 ks = KS[slot];
        u32 kb = KBa[slot];
        float4 bx = Bring[slot * 64 + lane];
        u64 I = Iring[slot * 64 + lane];
        if (ks != ~0ull) {
            float ar = (bx.z - bx.x) * (bx.w - bx.y);
            bool alive = valid && !((ks >> lane) & 1ull);
            u32 r1 = (kcur + 3) & ~3u;                    // top-up recent keeps
            for (u32 r = kb & ~3u; r < r1; r += 4) {
                float4 q0 = kbox[r], q1 = kbox[r + 1], q2 = kbox[r + 2], q3 = kbox[r + 3];
                float4 a4 = *(const float4*)(karea + r);
                bool s = iou3(bx, ar, q0, a4.x) | iou3(bx, ar, q1, a4.y)
                       | iou3(bx, ar, q2, a4.z) | iou3(bx, ar, q3, a4.w);
                alive = alive && !s;
            }
            u64 rem = __ballot(alive);
            if (rem) {
                u64 km = 0ull;
                while (rem) {                             // SALU keep chain
                    int pos = __ffsll((long long)rem) - 1;
                    km |= 1ull << pos;
                    if (++kept == MAX_BOXES) { capped = true; break; }
                    u32 lo = (u32)__builtin_amdgcn_readlane((int)(u32)I, pos);
                    u32 hi = (u32)__builtin_amdgcn_readlane((int)(u32)(I >> 32), pos);
                    rem &= ~(((u64)hi << 32) | (u64)lo);  // diag bit kills pos
                }
                if ((km >> lane) & 1ull) {
                    int rank = (int)__popcll(km & ((1ull << lane) - 1ull));
                    kbox[kcur + rank] = bx;
                    karea[kcur + rank] = ar;
                    kout[kcur + rank] = ((u64)__float_as_uint(sc) << 32) | j;
                }
                kcur += (u32)__popcll(km);
            }
        }
        if (capped) break;
        if (lane == 0) {
            __hip_atomic_store(kcnt, kcur, __ATOMIC_RELEASE, WG);
            __hip_atomic_store(prog, (u32)(k + 1), __ATOMIC_RELEASE, WG);
        }
        if (k + 1 < nch) key = lk[(k + 1) * 64 + lane];   // prefetch next chunk
    }
    if (lane == 0) __hip_atomic_store(prog, (u32)DONEP, __ATOMIC_RELEASE, WG);
    __builtin_amdgcn_s_setprio(0);

    // flush buffered keeps to global (off the serial chain)
    for (u32 i = (u32)lane; i < kcur; i += 64) {
        u64 e = kout[i];
        out[(size_t)((u32)e) * OUT_COLS + 4 + c] = __uint_as_float((u32)(e >> 32));
    }
}

extern "C" void kernel_launch(void* const* d_in, const int* in_sizes, int n_in,
                              void* d_out, int out_size, void* d_ws, size_t ws_size,
                              hipStream_t stream) {
    const float* cls = (const float*)d_in[1];
    float* out = (float*)d_out;
    nms<<<N_CLASSES, BLOCK, 0, stream>>>(cls, (const float4*)d_in[0], out);
}